// Round 4
// baseline (467.833 us; speedup 1.0000x reference)
//
#include <hip/hip_runtime.h>
#include <math.h>

// Problem constants
#define BB   64
#define CIN  16
#define LL   8192
#define CO   32
#define TCO  64
constexpr int T0n = 128;   // frames for n=64
constexpr int T1n = 32;    // frames for n=256
constexpr int F0n = 33;
constexpr int F1n = 129;

typedef unsigned int   uint32;
typedef unsigned short u16;
typedef __attribute__((ext_vector_type(8))) _Float16 half8;  // 8 f16 (4 VGPRs)
typedef __attribute__((ext_vector_type(4))) float    f32x4;  // MFMA accumulator
typedef __attribute__((ext_vector_type(4))) uint32   u32x4;

// sign-flip pattern (+,+,-,-,+,+,-,-) over a half8 B-frag: k2 = 8a+j -> f = 4a+(j>>1),
// (-1)^f over j flips j=2,3,6,7 = dwords 1 and 3.  Used for W row symmetry:
// W[m+N/2][k2] = (-1)^{f(k2)} * W[m][k2].
__device__ inline half8 flip_pm(half8 v) {
    u32x4 u;
    __builtin_memcpy(&u, &v, 16);
    u.y ^= 0x80008000u;
    u.w ^= 0x80008000u;
    half8 r;
    __builtin_memcpy(&r, &u, 16);
    return r;
}

// ---------------- STFT as GEMM: spec[t][j] = sum_k X[t][k] * D[k][j] -----------
// X: frames (reflect-padded, non-overlapping in padded coords), split f16 hi/lo
// D[k][2f]=cos(2pi f k/N), D[k][2f+1]=-sin(2pi f k/N)  (rfft convention)
// Output j-interleaved re/im == existing float2 p layout viewed as float.
template<int N, int F, int TFR, int NTILES, int KTT, int MT_W, int NT_W,
         int NT_STRIDE, bool MT_SPLIT>
__global__ __launch_bounds__(256)
void stft_mfma_kernel(const float* __restrict__ x,
                      const u16* __restrict__ dhi, const u16* __restrict__ dlo,
                      float* __restrict__ p) {
    constexpr int PADN = N + 8;            // +16B row pad -> 2-way LDS alias (free)
    __shared__ __align__(16) u16 Xhi[TFR * PADN];
    __shared__ __align__(16) u16 Xlo[TFR * PADN];
    int bc = blockIdx.x;                   // b*CIN + c
    const float* xrow = x + (size_t)bc * LL;

    for (int i = threadIdx.x; i < TFR * N; i += 256) {
        int row = i / N, colk = i % N;
        int gi = i - N / 2;                // xp[i] = x[i - N/2], reflect left
        gi = gi < 0 ? -gi : gi;
        float v = xrow[gi];
        _Float16 h = (_Float16)v;
        _Float16 l = (_Float16)(v - (float)h);
        Xhi[row * PADN + colk] = *(u16*)&h;
        Xlo[row * PADN + colk] = *(u16*)&l;
    }
    __syncthreads();

    int lane = threadIdx.x & 63, w = threadIdx.x >> 6;
    int col = lane & 15, quad = lane >> 4;
    f32x4 acc[MT_W][NT_W];
    #pragma unroll
    for (int mi = 0; mi < MT_W; ++mi)
        #pragma unroll
        for (int nj = 0; nj < NT_W; ++nj) {
            f32x4 z = {0.f, 0.f, 0.f, 0.f};
            acc[mi][nj] = z;
        }

    for (int kt = 0; kt < KTT; ++kt) {
        half8 ah[MT_W], al[MT_W];
        #pragma unroll
        for (int mi = 0; mi < MT_W; ++mi) {
            int mt = MT_SPLIT ? (w * MT_W + mi) : mi;
            int t  = mt * 16 + col;
            ah[mi] = *(const half8*)&Xhi[t * PADN + kt * 32 + quad * 8];
            al[mi] = *(const half8*)&Xlo[t * PADN + kt * 32 + quad * 8];
        }
        #pragma unroll
        for (int nj = 0; nj < NT_W; ++nj) {
            int nt = MT_SPLIT ? nj : (w + nj * NT_STRIDE);
            if (nt < NTILES) {
                half8 bh = ((const half8*)dhi)[(nt * KTT + kt) * 64 + lane];
                half8 bl = ((const half8*)dlo)[(nt * KTT + kt) * 64 + lane];
                #pragma unroll
                for (int mi = 0; mi < MT_W; ++mi) {
                    acc[mi][nj] = __builtin_amdgcn_mfma_f32_16x16x32_f16(ah[mi], bh, acc[mi][nj], 0, 0, 0);
                    acc[mi][nj] = __builtin_amdgcn_mfma_f32_16x16x32_f16(ah[mi], bl, acc[mi][nj], 0, 0, 0);
                    acc[mi][nj] = __builtin_amdgcn_mfma_f32_16x16x32_f16(al[mi], bh, acc[mi][nj], 0, 0, 0);
                }
            }
        }
    }

    int b = bc / CIN, c = bc % CIN;
    #pragma unroll
    for (int mi = 0; mi < MT_W; ++mi) {
        int mt = MT_SPLIT ? (w * MT_W + mi) : mi;
        #pragma unroll
        for (int nj = 0; nj < NT_W; ++nj) {
            int nt = MT_SPLIT ? nj : (w + nj * NT_STRIDE);
            if (nt < NTILES) {
                int j = nt * 16 + col;
                if (j < 2 * F) {
                    int t0 = mt * 16 + quad * 4;
                    f32x4 a = acc[mi][nj];
                    #pragma unroll
                    for (int r = 0; r < 4; ++r) {
                        p[(((size_t)b * TFR + t0 + r) * CIN + c) * (2 * F) + j] = a[r];
                    }
                }
            }
        }
    }
}

// ---------------- init: STFT D tables, B-fragment order, split fp16 ------------
__global__ __launch_bounds__(256)
void init_d_kernel(u16* __restrict__ dhi0, u16* __restrict__ dlo0,
                   u16* __restrict__ dhi1, u16* __restrict__ dlo1) {
    int idx = blockIdx.x * 256 + threadIdx.x;
    constexpr int SZ0 = 5 * 2 * 64 * 8;    // 5120
    constexpr int SZ1 = 17 * 8 * 64 * 8;   // 69632
    int N, F, KTT, id; u16 *dh, *dl;
    if (idx < SZ0)            { N = 64;  F = F0n; KTT = 2; dh = dhi0; dl = dlo0; id = idx; }
    else if (idx < SZ0 + SZ1) { N = 256; F = F1n; KTT = 8; dh = dhi1; dl = dlo1; id = idx - SZ0; }
    else return;
    int jj   = id & 7;
    int lane = (id >> 3) & 63;
    int rest = id >> 9;
    int kt   = rest % KTT;
    int nt   = rest / KTT;
    int j = nt * 16 + (lane & 15);
    int k = kt * 32 + (lane >> 4) * 8 + jj;
    float v = 0.f;
    if (j < 2 * F) {
        int f = j >> 1;
        int u = (f * k) % N;
        double th = 6.283185307179586476925286766559 * (double)u / (double)N;
        v = (float)((j & 1) ? -sin(th) : cos(th));
    }
    _Float16 h = (_Float16)v;
    _Float16 l = (_Float16)(v - (float)h);
    dh[id] = *(u16*)&h;
    dl[id] = *(u16*)&l;
}

// ---------------- merge (attention over 4 sub-frames), in-place into p1 --------
__global__ __launch_bounds__(256)
void merge_kernel(const float2* __restrict__ p0, float2* __restrict__ p1,
                  const float* __restrict__ mkr, const float* __restrict__ mki,
                  const float* __restrict__ mbr, const float* __restrict__ mbi) {
    int idx = blockIdx.x * 256 + threadIdx.x;
    const int total = BB * T1n * CIN * F0n;
    if (idx >= total) return;
    int f0 = idx % F0n; int r1 = idx / F0n;
    int c  = r1 % CIN;  int r2 = r1 / CIN;
    int t1 = r2 % T1n;  int b  = r2 / T1n;
    float2 pm[4];
    #pragma unroll
    for (int r = 0; r < 4; ++r) {
        int t = t1 * 4 + r;
        pm[r] = p0[(((size_t)b * T0n + t) * CIN + c) * F0n + f0];
    }
    float mag[4], mx = -1e30f;
    #pragma unroll
    for (int s = 0; s < 4; ++s) {
        float atr = mbr[s], ati = mbi[s];
        #pragma unroll
        for (int r = 0; r < 4; ++r) {
            float kr = mkr[r * 4 + s], ki = mki[r * 4 + s];
            atr = fmaf(pm[r].x, kr, atr); atr = fmaf(-pm[r].y, ki, atr);
            ati = fmaf(pm[r].x, ki, ati); ati = fmaf(pm[r].y, kr, ati);
        }
        mag[s] = sqrtf(atr * atr + ati * ati);
        mx = fmaxf(mx, mag[s]);
    }
    float se = 0.f;
    #pragma unroll
    for (int s = 0; s < 4; ++s) { mag[s] = expf(mag[s] - mx); se += mag[s]; }
    float inv = 4.0f / se;                 // RATIO / sum
    float mr = 0.f, mi = 0.f;
    #pragma unroll
    for (int r = 0; r < 4; ++r) { mr = fmaf(pm[r].x, mag[r], mr); mi = fmaf(pm[r].y, mag[r], mi); }
    p1[(((size_t)b * T1n + t1) * CIN + c) * F1n + 4 * f0] = make_float2(mr * inv, mi * inv);
}

// ---------------- complex batch-norm stats -> per-batch affine ------------------
__global__ __launch_bounds__(256)
void cbn_kernel(const float2* __restrict__ p0, const float2* __restrict__ p1,
                const float* __restrict__ gamma, const float* __restrict__ beta,
                float4* __restrict__ bn) {
    int head = blockIdx.x >> 6;
    int b    = blockIdx.x & 63;
    int Nel  = head ? (T1n * CIN * F1n) : (T0n * CIN * F0n);
    const float2* base = head ? (p1 + (size_t)b * (T1n * CIN * F1n))
                              : (p0 + (size_t)b * (T0n * CIN * F0n));
    float sr = 0.f, si = 0.f, s2 = 0.f;
    for (int i = threadIdx.x; i < Nel; i += 256) {
        float2 v = base[i];
        sr += v.x; si += v.y;
        s2 = fmaf(v.x, v.x, s2); s2 = fmaf(v.y, v.y, s2);
    }
    __shared__ float red[3][256];
    red[0][threadIdx.x] = sr; red[1][threadIdx.x] = si; red[2][threadIdx.x] = s2;
    __syncthreads();
    for (int off = 128; off > 0; off >>= 1) {
        if (threadIdx.x < off) {
            red[0][threadIdx.x] += red[0][threadIdx.x + off];
            red[1][threadIdx.x] += red[1][threadIdx.x + off];
            red[2][threadIdx.x] += red[2][threadIdx.x + off];
        }
        __syncthreads();
    }
    if (threadIdx.x == 0) {
        float invN = 1.f / (float)Nel;
        float mur = red[0][0] * invN, mui = red[1][0] * invN;
        float var = red[2][0] * invN - mur * mur - mui * mui;
        float g = gamma[head * BB + b] * rsqrtf(var + 1e-5f);
        bn[head * BB + b] = make_float4(g, beta[head * BB + b] - mur * g, -mui * g, 0.f);
    }
}

// ---------------- init: irfft twiddle matrix (HALF rows m < N/2), split fp16 ---
// W[m][k2]: k2=2f -> scale_f*cos(2*pi*m*f/N); k2=2f+1 -> -scale_f*sin(...)
// W scaled by 2^10; S scaled by 2^5; epilogue multiplies by 2^-15.
// Upper half rows (m+N/2) derived at runtime via (-1)^f B-frag sign flip.
// cfg0: 2 m-tiles x 3 kt; cfg1: 8 m-tiles x 9 kt.
__global__ __launch_bounds__(256)
void init_w_kernel(u16* __restrict__ whi0, u16* __restrict__ wlo0,
                   u16* __restrict__ whi1, u16* __restrict__ wlo1) {
    int idx = blockIdx.x * 256 + threadIdx.x;
    constexpr int SZ0 = 2 * 3 * 64 * 8;    // 3072
    constexpr int SZ1 = 8 * 9 * 64 * 8;    // 36864
    int N, F, KT, id; u16 *dh, *dl;
    if (idx < SZ0)            { N = 64;  F = F0n; KT = 3; dh = whi0; dl = wlo0; id = idx; }
    else if (idx < SZ0 + SZ1) { N = 256; F = F1n; KT = 9; dh = whi1; dl = wlo1; id = idx - SZ0; }
    else return;
    int j    = id & 7;
    int lane = (id >> 3) & 63;
    int rest = id >> 9;
    int kt   = rest % KT;
    int mt   = rest / KT;
    int m  = mt * 16 + (lane & 15);        // m < N/2 only
    int k2 = kt * 32 + (lane >> 4) * 8 + j;
    float v = 0.f;
    if (k2 < 2 * F) {
        int f = k2 >> 1;
        double scale = (f == 0 || f == F - 1) ? (1024.0 / N) : (2048.0 / N);
        int u = (m * f) % N;
        double th = 6.283185307179586476925286766559 * (double)u / (double)N;
        v = (float)((k2 & 1) ? (-scale * sin(th)) : (scale * cos(th)));
    }
    _Float16 h = (_Float16)v;
    _Float16 l = (_Float16)(v - (float)h);
    dh[id] = *(u16*)&h;
    dl[id] = *(u16*)&l;
}

// ---------------- init: fk tables repacked coalesced + per-(f,o) ci-sum --------
__global__ __launch_bounds__(256)
void init_fk_kernel(const float* __restrict__ r0, const float* __restrict__ i0,
                    const float* __restrict__ r1, const float* __restrict__ i1,
                    float4* __restrict__ q0, float4* __restrict__ q1,
                    float2* __restrict__ s0, float2* __restrict__ s1) {
    int idx = blockIdx.x * 256 + threadIdx.x;
    constexpr int NQ0 = 8 * F0n * 32;   // 8448
    constexpr int NQ1 = 8 * F1n * 32;   // 33024
    constexpr int NS0 = F0n * 32;       // 1056
    constexpr int NS1 = F1n * 32;       // 4128
    if (idx < NQ0) {
        int id = idx;
        int c2 = id / (F0n * 32); int rem = id % (F0n * 32);
        int f = rem >> 5, o = rem & 31;
        int s = (f * CIN + 2 * c2) * CO + o;
        q0[id] = make_float4(r0[s], i0[s], r0[s + CO], i0[s + CO]);
    } else if (idx < NQ0 + NQ1) {
        int id = idx - NQ0;
        int c2 = id / (F1n * 32); int rem = id % (F1n * 32);
        int f = rem >> 5, o = rem & 31;
        int s = (f * CIN + 2 * c2) * CO + o;
        q1[id] = make_float4(r1[s], i1[s], r1[s + CO], i1[s + CO]);
    } else if (idx < NQ0 + NQ1 + NS0) {
        int id = idx - NQ0 - NQ1;
        int f = id >> 5, o = id & 31;
        float sr = 0.f, si = 0.f;
        for (int ci = 0; ci < CIN; ++ci) {
            int s = (f * CIN + ci) * CO + o;
            sr += r0[s]; si += i0[s];
        }
        s0[id] = make_float2(sr, si);
    } else if (idx < NQ0 + NQ1 + NS0 + NS1) {
        int id = idx - NQ0 - NQ1 - NS0;
        int f = id >> 5, o = id & 31;
        float sr = 0.f, si = 0.f;
        for (int ci = 0; ci < CIN; ++ci) {
            int s = (f * CIN + ci) * CO + o;
            sr += r1[s]; si += i1[s];
        }
        s1[id] = make_float2(sr, si);
    }
}

// ---------------- einsum kernel: CBN-folded, frame-batched, writes S -----------
// S layout: [b*TFR + t][f][o] float2 (re,im)*32 — coalesced 8B/lane stores.
// Each block stages G frames in LDS and reads fkq ONCE per G frames
// (amortizes the 561KB/145KB table re-read that dominated the fused istft's L2).
template<int F, int TFR, int CH0, int G>
__global__ __launch_bounds__(256)
void einsum_kernel(const float2* __restrict__ p, const float4* __restrict__ fkq,
                   const float2* __restrict__ fks, const float4* __restrict__ bn,
                   float2* __restrict__ S) {
    constexpr int FCO = F * 32;
    constexpr int NG  = TFR / G;
    __shared__ float2 xs[G][CIN * F];
    int grp = blockIdx.x % NG, b = blockIdx.x / NG;
    float4 par = bn[(CH0 ? 1 : 0) * BB + b];   // (g, t_re, t_im, -)
    {
        const float4* a4 = (const float4*)(p + ((size_t)b * TFR + grp * G) * CIN * F);
        float4* x4 = (float4*)&xs[0][0];
        for (int i = threadIdx.x; i < G * CIN * F / 2; i += 256) x4[i] = a4[i];
    }
    __syncthreads();
    float2* Sg = S + ((size_t)b * TFR + (size_t)grp * G) * FCO;
    for (int i = threadIdx.x; i < FCO; i += 256) {
        int f = i >> 5;
        float4 kk[8];
        #pragma unroll
        for (int c2 = 0; c2 < 8; ++c2) kk[c2] = fkq[c2 * FCO + i];  // coalesced
        float2 fv = fks[i];
        float base_re = fmaf(par.y, fv.x, -par.z * fv.y);
        float base_im = fmaf(par.y, fv.y,  par.z * fv.x);
        #pragma unroll 4
        for (int g = 0; g < G; ++g) {
            float re = 0.f, im = 0.f;
            #pragma unroll
            for (int c2 = 0; c2 < 8; ++c2) {
                float2 xa = xs[g][(2 * c2) * F + f];       // LDS broadcast
                float2 xb = xs[g][(2 * c2 + 1) * F + f];
                float4 kkc = kk[c2];
                re = fmaf(xa.x, kkc.x, re); re = fmaf(-xa.y, kkc.y, re);
                im = fmaf(xa.x, kkc.y, im); im = fmaf(xa.y, kkc.x, im);
                re = fmaf(xb.x, kkc.z, re); re = fmaf(-xb.y, kkc.w, re);
                im = fmaf(xb.x, kkc.w, im); im = fmaf(xb.y, kkc.z, im);
            }
            Sg[(size_t)g * FCO + i] = make_float2(
                fmaf(par.x, re, base_re) * 32.f,
                fmaf(par.x, im, base_im) * 32.f);
        }
    }
}

// ---------------- irfft kernel: stage S -> split-f16 LDS, MFMA with W symmetry --
// grid: B*(TFR+1); frame TFR re-uses S of frame 0 (wrap frame).
// W table holds rows m < N/2 only; rows m+N/2 computed with (-1)^f-flipped
// B-frags (flip_pm) — halves W L2 traffic at equal MFMA count.
// head1: WBT=2, waves split M (base tiles w*2+mi), both n-tiles per wave.
// head0: WBT=1, wave = (base tile w>>1, n-tile w&1).
template<int N, int F, int TFR, int CH0, int KT, int KPAD, int WBT, bool NTSPLIT>
__global__ __launch_bounds__(256)
void irfft_kernel(const float2* __restrict__ S,
                  const u16* __restrict__ whi, const u16* __restrict__ wlo,
                  const float* __restrict__ pbias, float* __restrict__ out) {
    constexpr int FCO = F * 32;
    constexpr int WNT = NTSPLIT ? 1 : 2;
    __shared__ __align__(16) u16 Shi[32][KPAD];
    __shared__ __align__(16) u16 Slo[32][KPAD];
    int t  = blockIdx.x % (TFR + 1);
    int b  = blockIdx.x / (TFR + 1);
    int tf = (t == TFR) ? 0 : t;
    const float2* src = S + ((size_t)b * TFR + tf) * FCO;
    for (int i = threadIdx.x; i < FCO; i += 256) {
        float2 v = src[i];                  // coalesced; already CBN'd and *32
        int f = i >> 5, o = i & 31;
        _Float16 rh = (_Float16)v.x; _Float16 rl = (_Float16)(v.x - (float)rh);
        _Float16 ih = (_Float16)v.y; _Float16 il = (_Float16)(v.y - (float)ih);
        ((uint32*)&Shi[o][0])[f] = ((uint32)(*(u16*)&ih) << 16) | (uint32)(*(u16*)&rh);
        ((uint32*)&Slo[o][0])[f] = ((uint32)(*(u16*)&il) << 16) | (uint32)(*(u16*)&rl);
    }
    for (int i = threadIdx.x; i < 32 * (KT * 16 - F); i += 256) {
        constexpr int cols = KT * 16 - F;
        int o = i / cols, j = i - o * cols;
        ((uint32*)&Shi[o][0])[F + j] = 0;
        ((uint32*)&Slo[o][0])[F + j] = 0;
    }
    __syncthreads();

    int lane = threadIdx.x & 63, w = threadIdx.x >> 6;
    int col = lane & 15, quad = lane >> 4;
    f32x4 accB[WBT][WNT], accD[WBT][WNT];   // base rows m, derived rows m+N/2
    #pragma unroll
    for (int mi = 0; mi < WBT; ++mi)
        #pragma unroll
        for (int nj = 0; nj < WNT; ++nj) {
            f32x4 z = {0.f, 0.f, 0.f, 0.f};
            accB[mi][nj] = z; accD[mi][nj] = z;
        }
    for (int kt = 0; kt < KT; ++kt) {
        half8 bh[WNT], bl[WNT], bhm[WNT], blm[WNT];
        #pragma unroll
        for (int nj = 0; nj < WNT; ++nj) {
            int nt = NTSPLIT ? (w & 1) : nj;
            bh[nj]  = *(const half8*)&Shi[nt * 16 + col][kt * 32 + quad * 8];
            bl[nj]  = *(const half8*)&Slo[nt * 16 + col][kt * 32 + quad * 8];
            bhm[nj] = flip_pm(bh[nj]);
            blm[nj] = flip_pm(bl[nj]);
        }
        #pragma unroll
        for (int mi = 0; mi < WBT; ++mi) {
            int mt = NTSPLIT ? (w >> 1) : (w * WBT + mi);
            half8 ah = ((const half8*)whi)[(mt * KT + kt) * 64 + lane];
            half8 al = ((const half8*)wlo)[(mt * KT + kt) * 64 + lane];
            #pragma unroll
            for (int nj = 0; nj < WNT; ++nj) {
                accB[mi][nj] = __builtin_amdgcn_mfma_f32_16x16x32_f16(ah, bh[nj],  accB[mi][nj], 0, 0, 0);
                accB[mi][nj] = __builtin_amdgcn_mfma_f32_16x16x32_f16(ah, bl[nj],  accB[mi][nj], 0, 0, 0);
                accB[mi][nj] = __builtin_amdgcn_mfma_f32_16x16x32_f16(al, bh[nj],  accB[mi][nj], 0, 0, 0);
                accD[mi][nj] = __builtin_amdgcn_mfma_f32_16x16x32_f16(ah, bhm[nj], accD[mi][nj], 0, 0, 0);
                accD[mi][nj] = __builtin_amdgcn_mfma_f32_16x16x32_f16(ah, blm[nj], accD[mi][nj], 0, 0, 0);
                accD[mi][nj] = __builtin_amdgcn_mfma_f32_16x16x32_f16(al, bhm[nj], accD[mi][nj], 0, 0, 0);
            }
        }
    }
    constexpr float UNSCALE = 1.0f / 32768.0f;   // 2^-15 (W*2^10, S*2^5)
    size_t bb = (size_t)b * TCO;
    #pragma unroll
    for (int mi = 0; mi < WBT; ++mi) {
        int mt = NTSPLIT ? (w >> 1) : (w * WBT + mi);
        #pragma unroll
        for (int hh = 0; hh < 2; ++hh) {
            int m  = mt * 16 + quad * 4 + hh * (N / 2);
            int l0 = t * N + m - N / 2;
            if ((unsigned)l0 < LL) {
                #pragma unroll
                for (int nj = 0; nj < WNT; ++nj) {
                    int nt = NTSPLIT ? (w & 1) : nj;
                    int ch = CH0 + nt * 16 + col;
                    float pb = pbias[ch];
                    f32x4 a = hh ? accD[mi][nj] : accB[mi][nj];
                    float4 v;
                    v.x = fmaxf(fmaf(a[0], UNSCALE, pb), 0.f);
                    v.y = fmaxf(fmaf(a[1], UNSCALE, pb), 0.f);
                    v.z = fmaxf(fmaf(a[2], UNSCALE, pb), 0.f);
                    v.w = fmaxf(fmaf(a[3], UNSCALE, pb), 0.f);
                    *(float4*)(out + (bb + ch) * LL + l0) = v;
                }
            }
        }
    }
}

extern "C" void kernel_launch(void* const* d_in, const int* in_sizes, int n_in,
                              void* d_out, int out_size, void* d_ws, size_t ws_size,
                              hipStream_t stream) {
    const float* x     = (const float*)d_in[0];
    const float* gam   = (const float*)d_in[1];
    const float* bet   = (const float*)d_in[2];
    const float* mkr   = (const float*)d_in[3];
    const float* mki   = (const float*)d_in[4];
    const float* mbr   = (const float*)d_in[5];
    const float* mbi   = (const float*)d_in[6];
    const float* fk0r  = (const float*)d_in[7];
    const float* fk0i  = (const float*)d_in[8];
    const float* fk1r  = (const float*)d_in[9];
    const float* fk1i  = (const float*)d_in[10];
    const float* pbias = (const float*)d_in[11];
    float* out = (float*)d_out;

    float2* p0   = (float2*)d_ws;                                   // 34.6 MB
    float2* p1   = p0 + (size_t)BB * T0n * CIN * F0n;               // 33.8 MB
    float4* bnp  = (float4*)(p1 + (size_t)BB * T1n * CIN * F1n);    // 2 KB
    float4* fkq0 = bnp + 2 * BB;                                    // 132 KB
    float4* fkq1 = fkq0 + 8 * F0n * 32;                             // 516 KB
    float2* fks0 = (float2*)(fkq1 + 8 * F1n * 32);                  // 8 KB
    float2* fks1 = fks0 + F0n * 32;                                 // 33 KB
    float2* Sbuf = fks1 + F1n * 32;                                 // 69.2 MB (shared by both heads)
    u16*    whi0 = (u16*)(Sbuf + (size_t)BB * T0n * F0n * 32);      // 6 KB
    u16*    wlo0 = whi0 + 3072;
    u16*    whi1 = wlo0 + 3072;                                     // 72 KB
    u16*    wlo1 = whi1 + 36864;
    u16*    dhi0 = wlo1 + 36864;                                    // 10 KB
    u16*    dlo0 = dhi0 + 5120;
    u16*    dhi1 = dlo0 + 5120;                                     // 139 KB
    u16*    dlo1 = dhi1 + 69632;

    init_w_kernel<<<(3072 + 36864 + 255) / 256, 256, 0, stream>>>(whi0, wlo0, whi1, wlo1);
    init_d_kernel<<<(5120 + 69632 + 255) / 256, 256, 0, stream>>>(dhi0, dlo0, dhi1, dlo1);
    init_fk_kernel<<<(8 * (F0n + F1n) * 32 + (F0n + F1n) * 32 + 255) / 256, 256, 0, stream>>>(
        fk0r, fk0i, fk1r, fk1i, fkq0, fkq1, fks0, fks1);
    // cfg64:  M=128 (8 tiles, waves split M), N-tiles=5, K=64  (2 ksteps)
    stft_mfma_kernel<64, F0n, 128, 5, 2, 2, 5, 1, true><<<BB * CIN, 256, 0, stream>>>(
        x, dhi0, dlo0, (float*)p0);
    // cfg256: M=32 (2 tiles, both per wave), N-tiles=17 (waves stride 4), K=256 (8 ksteps)
    stft_mfma_kernel<256, F1n, 32, 17, 8, 2, 5, 4, false><<<BB * CIN, 256, 0, stream>>>(
        x, dhi1, dlo1, (float*)p1);
    merge_kernel<<<(BB * T1n * CIN * F0n) / 256, 256, 0, stream>>>(p0, p1, mkr, mki, mbr, mbi);
    cbn_kernel<<<128, 256, 0, stream>>>(p0, p1, gam, bet, bnp);
    // head1 then head0, sharing Sbuf (stream order makes reuse safe)
    einsum_kernel<F1n, T1n, 32, 4><<<BB * (T1n / 4), 256, 0, stream>>>(
        p1, fkq1, fks1, bnp, Sbuf);
    irfft_kernel<256, F1n, T1n, 32, 9, 296, 2, false><<<BB * (T1n + 1), 256, 0, stream>>>(
        Sbuf, whi1, wlo1, pbias, out);
    einsum_kernel<F0n, T0n, 0, 16><<<BB * (T0n / 16), 256, 0, stream>>>(
        p0, fkq0, fks0, bnp, Sbuf);
    irfft_kernel<64, F0n, T0n, 0, 3, 104, 1, true><<<BB * (T0n + 1), 256, 0, stream>>>(
        Sbuf, whi0, wlo0, pbias, out);
}